// Round 4
// baseline (136.653 us; speedup 1.0000x reference)
//
#include <hip/hip_runtime.h>
#include <hip/hip_bf16.h>

// Packed parameter block in d_ws (floats):
//  [0    .. 255]   Vr[16][16]   (Re of V = U * diag((-i)^popcount(col)))
//  [256  .. 511]   Vi[16][16]
//  [512  .. 767]   WpT[64][4]   (WpT[f][q] = Wp[q][f])
//  [768  .. 771]   bp[4]
//  [772  .. 1155]  MLP pack: per j in 0..63: {W1[j][0..3], b1[j], W2[j]}
//  [1156]          b2
#define CBUF_N 1157

// ---------------- precompute: build V and pack weights into ws ----------------

__device__ inline void gate_rz(float* ar, float* ai, int q, float th) {
    float c = cosf(0.5f * th), s = sinf(0.5f * th);
    int st = 8 >> q;
    #pragma unroll
    for (int k = 0; k < 16; k++) {
        float r = ar[k], im = ai[k];
        if (k & st) {            // * e^{+i th/2}
            ar[k] = r * c - im * s;
            ai[k] = im * c + r * s;
        } else {                 // * e^{-i th/2}
            ar[k] = r * c + im * s;
            ai[k] = im * c - r * s;
        }
    }
}

__device__ inline void gate_ry(float* ar, float* ai, int q, float th) {
    float c = cosf(0.5f * th), s = sinf(0.5f * th);
    int st = 8 >> q;
    #pragma unroll
    for (int k = 0; k < 16; k++) {
        if (!(k & st)) {
            int k1 = k | st;
            float r0 = ar[k], i0 = ai[k], r1 = ar[k1], i1 = ai[k1];
            ar[k]  = c * r0 - s * r1;  ai[k]  = c * i0 - s * i1;
            ar[k1] = s * r0 + c * r1;  ai[k1] = s * i0 + c * i1;
        }
    }
}

__device__ inline void gate_cnot(float* ar, float* ai, int c, int t) {
    int stc = 8 >> c, stt = 8 >> t;
    #pragma unroll
    for (int k = 0; k < 16; k++) {
        if ((k & stc) && !(k & stt)) {
            int k1 = k | stt;
            float r = ar[k], im = ai[k];
            ar[k] = ar[k1]; ai[k] = ai[k1];
            ar[k1] = r;     ai[k1] = im;
        }
    }
}

__global__ void precompute_kernel(const float* __restrict__ Wp,
                                  const float* __restrict__ bp,
                                  const float* __restrict__ wq,
                                  const float* __restrict__ W1,
                                  const float* __restrict__ b1,
                                  const float* __restrict__ W2,
                                  const float* __restrict__ b2,
                                  float* __restrict__ ws) {
    int t = threadIdx.x;  // 64 threads

    if (t < 16) {
        // Simulate the fixed part of the circuit on basis state e_t -> column t of U.
        float ar[16], ai[16];
        #pragma unroll
        for (int k = 0; k < 16; k++) { ar[k] = 0.f; ai[k] = 0.f; }
        ar[t] = 1.f;

        for (int layer = 0; layer < 2; layer++) {
            for (int q = 0; q < 4; q++) {
                const float* w = &wq[(layer * 4 + q) * 3];
                gate_rz(ar, ai, q, w[0]);
                gate_ry(ar, ai, q, w[1]);
                gate_rz(ar, ai, q, w[2]);
            }
            for (int c = 0; c < 3; c++) gate_cnot(ar, ai, c, c + 1);
        }

        // fold phase (-i)^popcount(t) of the RX product state into column t
        int pc = __popc(t) & 3;
        #pragma unroll
        for (int j = 0; j < 16; j++) {
            float re = ar[j], im = ai[j], vr, vi;
            switch (pc) {
                case 0: vr = re;  vi = im;  break;
                case 1: vr = im;  vi = -re; break;   // *(-i)
                case 2: vr = -re; vi = -im; break;   // *(-1)
                case 3: vr = -im; vi = re;  break;   // *(+i)
            }
            ws[j * 16 + t]       = vr;
            ws[256 + j * 16 + t] = vi;
        }
    }

    // WpT pack: ws[512 + f*4 + q] = Wp[q*64 + f], f = t
    for (int q = 0; q < 4; q++) ws[512 + t * 4 + q] = Wp[q * 64 + t];
    if (t < 4) ws[768 + t] = bp[t];

    // MLP pack, row j = t
    ws[772 + t * 6 + 0] = W1[t * 4 + 0];
    ws[772 + t * 6 + 1] = W1[t * 4 + 1];
    ws[772 + t * 6 + 2] = W1[t * 4 + 2];
    ws[772 + t * 6 + 3] = W1[t * 4 + 3];
    ws[772 + t * 6 + 4] = b1[t];
    ws[772 + t * 6 + 5] = W2[t];
    if (t == 0) ws[1156] = b2[0];
}

// ---------------- main kernel ----------------
// Block = 256 threads = 256 rows, two 32-column stages through LDS.
// Round-4 changes vs R3:
//  * LDS row stride = 36 floats (144 B, 16-B aligned) -> single ds_write_b128 /
//    ds_read_b128 per float4 (32 LDS instr/thread vs 128). The stride-36
//    8-lane bank aliasing still keeps all 32 banks busy per phase (at the
//    1 KiB/instr data-volume floor).
//  * stage-1 global loads are issued into registers BEFORE stage-0 compute
//    (software pipeline: no memory-latency bubble between stages).
//  * __launch_bounds__(256,4): pin 4 waves/EU (16 waves/CU, 4 blocks/CU).

__global__ __launch_bounds__(256, 4) void qmain_kernel(const float* __restrict__ x,
                                                       const float* __restrict__ cb,
                                                       float* __restrict__ out,
                                                       int B) {
    __shared__ float tile[256 * 36];
    const int t = threadIdx.x;
    const long row0 = (long)blockIdx.x * 256;
    const float* xb = x + row0 * 64;

    // lane -> (row, col) for the cooperative 256x32 stage load
    const int lrow = t >> 3;        // 0..31 (x32 per r-iter)
    const int lcol = (t & 7) * 4;   // 0,4,...,28

    // ---- issue stage-0 loads ----
    float4 v0[8];
    #pragma unroll
    for (int r = 0; r < 8; r++) {
        int row = r * 32 + lrow;
        v0[r] = *reinterpret_cast<const float4*>(xb + row * 64 + lcol);
    }
    // ---- issue stage-1 loads (prefetch; consumed after stage-0 compute) ----
    float4 v1[8];
    #pragma unroll
    for (int r = 0; r < 8; r++) {
        int row = r * 32 + lrow;
        v1[r] = *reinterpret_cast<const float4*>(xb + row * 64 + 32 + lcol);
    }

    float ang[4];
    #pragma unroll
    for (int q = 0; q < 4; q++) ang[q] = cb[768 + q];

    // ---- stage 0: LDS write (b128), sync, consume ----
    #pragma unroll
    for (int r = 0; r < 8; r++) {
        int row = r * 32 + lrow;
        *reinterpret_cast<float4*>(&tile[row * 36 + lcol]) = v0[r];
    }
    __syncthreads();
    {
        const float4* myrow4 = reinterpret_cast<const float4*>(&tile[t * 36]);
        #pragma unroll
        for (int i = 0; i < 8; i++) {
            float4 xv = myrow4[i];
            const float* w = &cb[512 + (i * 4) * 4];
            #pragma unroll
            for (int q = 0; q < 4; q++) {
                ang[q] = fmaf(xv.x, w[q],      ang[q]);
                ang[q] = fmaf(xv.y, w[4 + q],  ang[q]);
                ang[q] = fmaf(xv.z, w[8 + q],  ang[q]);
                ang[q] = fmaf(xv.w, w[12 + q], ang[q]);
            }
        }
    }
    __syncthreads();

    // ---- stage 1: LDS write from prefetched regs, sync, consume ----
    #pragma unroll
    for (int r = 0; r < 8; r++) {
        int row = r * 32 + lrow;
        *reinterpret_cast<float4*>(&tile[row * 36 + lcol]) = v1[r];
    }
    __syncthreads();
    {
        const float4* myrow4 = reinterpret_cast<const float4*>(&tile[t * 36]);
        #pragma unroll
        for (int i = 0; i < 8; i++) {
            float4 xv = myrow4[i];
            const float* w = &cb[512 + (32 + i * 4) * 4];
            #pragma unroll
            for (int q = 0; q < 4; q++) {
                ang[q] = fmaf(xv.x, w[q],      ang[q]);
                ang[q] = fmaf(xv.y, w[4 + q],  ang[q]);
                ang[q] = fmaf(xv.z, w[8 + q],  ang[q]);
                ang[q] = fmaf(xv.w, w[12 + q], ang[q]);
            }
        }
    }

    // ---- RX product-state magnitudes m[16] ----
    float c[4], s4[4];
    #pragma unroll
    for (int q = 0; q < 4; q++) {
        __sincosf(0.5f * ang[q], &s4[q], &c[q]);
    }
    float pre[4]  = { c[0] * c[1], c[0] * s4[1], s4[0] * c[1], s4[0] * s4[1] };
    float post[4] = { c[2] * c[3], c[2] * s4[3], s4[2] * c[3], s4[2] * s4[3] };
    float m[16];
    #pragma unroll
    for (int k = 0; k < 16; k++) m[k] = pre[k >> 2] * post[k & 3];

    // ---- phi = V m ; p = |phi|^2 ; z = signed sums ----
    float z0 = 0.f, z1 = 0.f, z2 = 0.f, z3 = 0.f;
    #pragma unroll
    for (int j = 0; j < 16; j++) {
        const float* vr = &cb[j * 16];
        const float* vi = &cb[256 + j * 16];
        float re = 0.f, im = 0.f;
        #pragma unroll
        for (int k = 0; k < 16; k++) {
            re = fmaf(vr[k], m[k], re);
            im = fmaf(vi[k], m[k], im);
        }
        float p = re * re + im * im;
        z0 += (j & 8) ? -p : p;
        z1 += (j & 4) ? -p : p;
        z2 += (j & 2) ? -p : p;
        z3 += (j & 1) ? -p : p;
    }

    // ---- MLP: out = W2 @ relu(W1 @ z + b1) + b2 ----
    float acc = cb[1156];
    #pragma unroll
    for (int j = 0; j < 64; j++) {
        const float* mp = &cb[772 + j * 6];
        float h = mp[4];
        h = fmaf(mp[0], z0, h);
        h = fmaf(mp[1], z1, h);
        h = fmaf(mp[2], z2, h);
        h = fmaf(mp[3], z3, h);
        h = fmaxf(h, 0.f);
        acc = fmaf(mp[5], h, acc);
    }
    out[row0 + t] = acc;
}

// ---------------- launch ----------------

extern "C" void kernel_launch(void* const* d_in, const int* in_sizes, int n_in,
                              void* d_out, int out_size, void* d_ws, size_t ws_size,
                              hipStream_t stream) {
    const float* x  = (const float*)d_in[0];
    const float* Wp = (const float*)d_in[1];
    const float* bp = (const float*)d_in[2];
    const float* wq = (const float*)d_in[3];
    const float* W1 = (const float*)d_in[4];
    const float* b1 = (const float*)d_in[5];
    const float* W2 = (const float*)d_in[6];
    const float* b2 = (const float*)d_in[7];
    float* ws = (float*)d_ws;
    float* out = (float*)d_out;

    int B = in_sizes[0] / 64;

    precompute_kernel<<<1, 64, 0, stream>>>(Wp, bp, wq, W1, b1, W2, b2, ws);

    int grid = (B + 255) / 256;   // 1024 blocks, 256 rows each
    qmain_kernel<<<grid, 256, 0, stream>>>(x, ws, out, B);
}

// Round 5
// 131.538 us; speedup vs baseline: 1.0389x; 1.0389x over previous
//
#include <hip/hip_runtime.h>
#include <hip/hip_bf16.h>

// Packed parameter block in d_ws (floats):
//  [0    .. 255]   Vr[16][16]   (Re of V = U * diag((-i)^popcount(col)))
//  [256  .. 511]   Vi[16][16]
//  [512  .. 767]   WpT[64][4]   (WpT[f][q] = Wp[q][f])
//  [768  .. 771]   bp[4]
//  [772  .. 1155]  MLP pack: per j in 0..63: {W1[j][0..3], b1[j], W2[j]}
//  [1156]          b2
#define CBUF_N 1157

// ---------------- precompute: build V and pack weights into ws ----------------

__device__ inline void gate_rz(float* ar, float* ai, int q, float th) {
    float c = cosf(0.5f * th), s = sinf(0.5f * th);
    int st = 8 >> q;
    #pragma unroll
    for (int k = 0; k < 16; k++) {
        float r = ar[k], im = ai[k];
        if (k & st) {            // * e^{+i th/2}
            ar[k] = r * c - im * s;
            ai[k] = im * c + r * s;
        } else {                 // * e^{-i th/2}
            ar[k] = r * c + im * s;
            ai[k] = im * c - r * s;
        }
    }
}

__device__ inline void gate_ry(float* ar, float* ai, int q, float th) {
    float c = cosf(0.5f * th), s = sinf(0.5f * th);
    int st = 8 >> q;
    #pragma unroll
    for (int k = 0; k < 16; k++) {
        if (!(k & st)) {
            int k1 = k | st;
            float r0 = ar[k], i0 = ai[k], r1 = ar[k1], i1 = ai[k1];
            ar[k]  = c * r0 - s * r1;  ai[k]  = c * i0 - s * i1;
            ar[k1] = s * r0 + c * r1;  ai[k1] = s * i0 + c * i1;
        }
    }
}

__device__ inline void gate_cnot(float* ar, float* ai, int c, int t) {
    int stc = 8 >> c, stt = 8 >> t;
    #pragma unroll
    for (int k = 0; k < 16; k++) {
        if ((k & stc) && !(k & stt)) {
            int k1 = k | stt;
            float r = ar[k], im = ai[k];
            ar[k] = ar[k1]; ai[k] = ai[k1];
            ar[k1] = r;     ai[k1] = im;
        }
    }
}

__global__ void precompute_kernel(const float* __restrict__ Wp,
                                  const float* __restrict__ bp,
                                  const float* __restrict__ wq,
                                  const float* __restrict__ W1,
                                  const float* __restrict__ b1,
                                  const float* __restrict__ W2,
                                  const float* __restrict__ b2,
                                  float* __restrict__ ws) {
    int t = threadIdx.x;  // 64 threads

    if (t < 16) {
        // Simulate the fixed part of the circuit on basis state e_t -> column t of U.
        float ar[16], ai[16];
        #pragma unroll
        for (int k = 0; k < 16; k++) { ar[k] = 0.f; ai[k] = 0.f; }
        ar[t] = 1.f;

        for (int layer = 0; layer < 2; layer++) {
            for (int q = 0; q < 4; q++) {
                const float* w = &wq[(layer * 4 + q) * 3];
                gate_rz(ar, ai, q, w[0]);
                gate_ry(ar, ai, q, w[1]);
                gate_rz(ar, ai, q, w[2]);
            }
            for (int c = 0; c < 3; c++) gate_cnot(ar, ai, c, c + 1);
        }

        // fold phase (-i)^popcount(t) of the RX product state into column t
        int pc = __popc(t) & 3;
        #pragma unroll
        for (int j = 0; j < 16; j++) {
            float re = ar[j], im = ai[j], vr, vi;
            switch (pc) {
                case 0: vr = re;  vi = im;  break;
                case 1: vr = im;  vi = -re; break;   // *(-i)
                case 2: vr = -re; vi = -im; break;   // *(-1)
                case 3: vr = -im; vi = re;  break;   // *(+i)
            }
            ws[j * 16 + t]       = vr;
            ws[256 + j * 16 + t] = vi;
        }
    }

    // WpT pack: ws[512 + f*4 + q] = Wp[q*64 + f], f = t
    for (int q = 0; q < 4; q++) ws[512 + t * 4 + q] = Wp[q * 64 + t];
    if (t < 4) ws[768 + t] = bp[t];

    // MLP pack, row j = t
    ws[772 + t * 6 + 0] = W1[t * 4 + 0];
    ws[772 + t * 6 + 1] = W1[t * 4 + 1];
    ws[772 + t * 6 + 2] = W1[t * 4 + 2];
    ws[772 + t * 6 + 3] = W1[t * 4 + 3];
    ws[772 + t * 6 + 4] = b1[t];
    ws[772 + t * 6 + 5] = W2[t];
    if (t == 0) ws[1156] = b2[0];
}

// ---------------- main kernel ----------------
// NO LDS staging. Each wave owns 64 rows. Round r (0..3): lane L computes a
// quarter-dot of row r*16+(L>>2) over cols (L&3)*16..+15; wave loads are
// perfectly contiguous (4 KB/round). Quad DPP xor1/xor2 adds finish the dot;
// lane L latches round r == (L&3), so every lane ends with a distinct row.
// Weights for a lane's col-chunk (64 floats) are hoisted into 16 VGPR float4s
// (1 KB L1-resident table, reused across rounds). ds_bpermute restores
// row-order for a coalesced final store. Zero barriers, zero bank conflicts.

__device__ __forceinline__ float quad_allsum(float v) {
    // sum across each group of 4 lanes; result on all 4 lanes
    v += __int_as_float(__builtin_amdgcn_mov_dpp(__float_as_int(v), 0xB1, 0xF, 0xF, true)); // quad_perm [1,0,3,2]
    v += __int_as_float(__builtin_amdgcn_mov_dpp(__float_as_int(v), 0x4E, 0xF, 0xF, true)); // quad_perm [2,3,0,1]
    return v;
}

__global__ __launch_bounds__(256, 3) void qmain_kernel(const float* __restrict__ x,
                                                       const float* __restrict__ cb,
                                                       float* __restrict__ out,
                                                       int B) {
    const int lane = threadIdx.x & 63;
    const int wv   = threadIdx.x >> 6;                       // wave in block 0..3
    const long rows_base = (long)blockIdx.x * 256 + wv * 64; // this wave's 64 rows
    const float* xw = x + rows_base * 64;
    const int sub = lane & 3;                                // col-chunk / latch round

    // per-lane weights: columns sub*16 .. sub*16+15, each float4 = 4 q-weights
    const float4* cb4 = reinterpret_cast<const float4*>(cb);
    float4 wreg[16];
    #pragma unroll
    for (int j = 0; j < 16; j++) wreg[j] = cb4[128 + sub * 16 + j];  // 512/4 = 128

    float ang0 = cb[768], ang1 = cb[769], ang2 = cb[770], ang3 = cb[771];

    // two-deep pipeline over rounds
    float4 cur[4], nxt[4];
    {
        const float* p = xw + lane * 16;
        #pragma unroll
        for (int j = 0; j < 4; j++) cur[j] = *reinterpret_cast<const float4*>(p + 4 * j);
    }

    #pragma unroll
    for (int r = 0; r < 4; r++) {
        if (r < 3) {
            const float* p = xw + (r + 1) * 1024 + lane * 16;
            #pragma unroll
            for (int j = 0; j < 4; j++) nxt[j] = *reinterpret_cast<const float4*>(p + 4 * j);
        }
        float p0 = 0.f, p1 = 0.f, p2 = 0.f, p3 = 0.f;
        #pragma unroll
        for (int j = 0; j < 4; j++) {
            float4 xv = cur[j];
            float4 w0 = wreg[j * 4 + 0];
            float4 w1 = wreg[j * 4 + 1];
            float4 w2 = wreg[j * 4 + 2];
            float4 w3 = wreg[j * 4 + 3];
            p0 = fmaf(xv.x, w0.x, p0); p1 = fmaf(xv.x, w0.y, p1);
            p2 = fmaf(xv.x, w0.z, p2); p3 = fmaf(xv.x, w0.w, p3);
            p0 = fmaf(xv.y, w1.x, p0); p1 = fmaf(xv.y, w1.y, p1);
            p2 = fmaf(xv.y, w1.z, p2); p3 = fmaf(xv.y, w1.w, p3);
            p0 = fmaf(xv.z, w2.x, p0); p1 = fmaf(xv.z, w2.y, p1);
            p2 = fmaf(xv.z, w2.z, p2); p3 = fmaf(xv.z, w2.w, p3);
            p0 = fmaf(xv.w, w3.x, p0); p1 = fmaf(xv.w, w3.y, p1);
            p2 = fmaf(xv.w, w3.z, p2); p3 = fmaf(xv.w, w3.w, p3);
        }
        float r0 = quad_allsum(p0);
        float r1 = quad_allsum(p1);
        float r2 = quad_allsum(p2);
        float r3 = quad_allsum(p3);
        if (sub == r) { ang0 += r0; ang1 += r1; ang2 += r2; ang3 += r3; }  // cndmask
        #pragma unroll
        for (int j = 0; j < 4; j++) cur[j] = nxt[j];
    }

    float ang[4] = { ang0, ang1, ang2, ang3 };

    // ---- RX product-state magnitudes m[16] ----
    float c[4], s4[4];
    #pragma unroll
    for (int q = 0; q < 4; q++) {
        __sincosf(0.5f * ang[q], &s4[q], &c[q]);
    }
    float pre[4]  = { c[0] * c[1], c[0] * s4[1], s4[0] * c[1], s4[0] * s4[1] };
    float post[4] = { c[2] * c[3], c[2] * s4[3], s4[2] * c[3], s4[2] * s4[3] };
    float m[16];
    #pragma unroll
    for (int k = 0; k < 16; k++) m[k] = pre[k >> 2] * post[k & 3];

    // ---- phi = V m ; p = |phi|^2 ; z = signed sums ----
    float z0 = 0.f, z1 = 0.f, z2 = 0.f, z3 = 0.f;
    #pragma unroll
    for (int j = 0; j < 16; j++) {
        const float* vr = &cb[j * 16];
        const float* vi = &cb[256 + j * 16];
        float re = 0.f, im = 0.f;
        #pragma unroll
        for (int k = 0; k < 16; k++) {
            re = fmaf(vr[k], m[k], re);
            im = fmaf(vi[k], m[k], im);
        }
        float p = re * re + im * im;
        z0 += (j & 8) ? -p : p;
        z1 += (j & 4) ? -p : p;
        z2 += (j & 2) ? -p : p;
        z3 += (j & 1) ? -p : p;
    }

    // ---- MLP: out = W2 @ relu(W1 @ z + b1) + b2 ----
    float acc = cb[1156];
    #pragma unroll
    for (int j = 0; j < 64; j++) {
        const float* mp = &cb[772 + j * 6];
        float h = mp[4];
        h = fmaf(mp[0], z0, h);
        h = fmaf(mp[1], z1, h);
        h = fmaf(mp[2], z2, h);
        h = fmaf(mp[3], z3, h);
        h = fmaxf(h, 0.f);
        acc = fmaf(mp[5], h, acc);
    }

    // lane L holds row sub*16 + (L>>2); pull so lane L holds row L, store coalesced.
    // src lane for dest L: S = (L&15)*4 + (L>>4)  (row_local(S) == L)
    int srcb = (((lane & 15) * 4) + (lane >> 4)) * 4;   // byte index for bpermute
    float accL = __int_as_float(__builtin_amdgcn_ds_bpermute(srcb, __float_as_int(acc)));
    out[rows_base + lane] = accL;
}

// ---------------- launch ----------------

extern "C" void kernel_launch(void* const* d_in, const int* in_sizes, int n_in,
                              void* d_out, int out_size, void* d_ws, size_t ws_size,
                              hipStream_t stream) {
    const float* x  = (const float*)d_in[0];
    const float* Wp = (const float*)d_in[1];
    const float* bp = (const float*)d_in[2];
    const float* wq = (const float*)d_in[3];
    const float* W1 = (const float*)d_in[4];
    const float* b1 = (const float*)d_in[5];
    const float* W2 = (const float*)d_in[6];
    const float* b2 = (const float*)d_in[7];
    float* ws = (float*)d_ws;
    float* out = (float*)d_out;

    int B = in_sizes[0] / 64;   // 262144; divisible by 256 in this harness

    precompute_kernel<<<1, 64, 0, stream>>>(Wp, bp, wq, W1, b1, W2, b2, ws);

    int grid = B / 256;   // 1024 blocks, 256 rows each
    qmain_kernel<<<grid, 256, 0, stream>>>(x, ws, out, B);
}

// Round 6
// 124.826 us; speedup vs baseline: 1.0948x; 1.0538x over previous
//
#include <hip/hip_runtime.h>
#include <hip/hip_bf16.h>

// Packed parameter block in d_ws (floats):
//  [0    .. 255]   Vr[16][16]   (Re of V = U * diag((-i)^popcount(col)))
//  [256  .. 511]   Vi[16][16]
//  [512  .. 767]   WpT[64][4]   (WpT[f][q] = Wp[q][f])
//  [768  .. 771]   bp[4]
//  [772  .. 1155]  MLP pack: per j in 0..63: {W1[j][0..3], b1[j], W2[j]}
//  [1156]          b2
#define CBUF_N 1157

// ---------------- precompute: build V and pack weights into ws ----------------

__device__ inline void gate_rz(float* ar, float* ai, int q, float th) {
    float c = cosf(0.5f * th), s = sinf(0.5f * th);
    int st = 8 >> q;
    #pragma unroll
    for (int k = 0; k < 16; k++) {
        float r = ar[k], im = ai[k];
        if (k & st) {            // * e^{+i th/2}
            ar[k] = r * c - im * s;
            ai[k] = im * c + r * s;
        } else {                 // * e^{-i th/2}
            ar[k] = r * c + im * s;
            ai[k] = im * c - r * s;
        }
    }
}

__device__ inline void gate_ry(float* ar, float* ai, int q, float th) {
    float c = cosf(0.5f * th), s = sinf(0.5f * th);
    int st = 8 >> q;
    #pragma unroll
    for (int k = 0; k < 16; k++) {
        if (!(k & st)) {
            int k1 = k | st;
            float r0 = ar[k], i0 = ai[k], r1 = ar[k1], i1 = ai[k1];
            ar[k]  = c * r0 - s * r1;  ai[k]  = c * i0 - s * i1;
            ar[k1] = s * r0 + c * r1;  ai[k1] = s * i0 + c * i1;
        }
    }
}

__device__ inline void gate_cnot(float* ar, float* ai, int c, int t) {
    int stc = 8 >> c, stt = 8 >> t;
    #pragma unroll
    for (int k = 0; k < 16; k++) {
        if ((k & stc) && !(k & stt)) {
            int k1 = k | stt;
            float r = ar[k], im = ai[k];
            ar[k] = ar[k1]; ai[k] = ai[k1];
            ar[k1] = r;     ai[k1] = im;
        }
    }
}

__global__ void precompute_kernel(const float* __restrict__ Wp,
                                  const float* __restrict__ bp,
                                  const float* __restrict__ wq,
                                  const float* __restrict__ W1,
                                  const float* __restrict__ b1,
                                  const float* __restrict__ W2,
                                  const float* __restrict__ b2,
                                  float* __restrict__ ws) {
    int t = threadIdx.x;  // 64 threads

    if (t < 16) {
        // Simulate the fixed part of the circuit on basis state e_t -> column t of U.
        float ar[16], ai[16];
        #pragma unroll
        for (int k = 0; k < 16; k++) { ar[k] = 0.f; ai[k] = 0.f; }
        ar[t] = 1.f;

        for (int layer = 0; layer < 2; layer++) {
            for (int q = 0; q < 4; q++) {
                const float* w = &wq[(layer * 4 + q) * 3];
                gate_rz(ar, ai, q, w[0]);
                gate_ry(ar, ai, q, w[1]);
                gate_rz(ar, ai, q, w[2]);
            }
            for (int c = 0; c < 3; c++) gate_cnot(ar, ai, c, c + 1);
        }

        // fold phase (-i)^popcount(t) of the RX product state into column t
        int pc = __popc(t) & 3;
        #pragma unroll
        for (int j = 0; j < 16; j++) {
            float re = ar[j], im = ai[j], vr, vi;
            switch (pc) {
                case 0: vr = re;  vi = im;  break;
                case 1: vr = im;  vi = -re; break;   // *(-i)
                case 2: vr = -re; vi = -im; break;   // *(-1)
                case 3: vr = -im; vi = re;  break;   // *(+i)
            }
            ws[j * 16 + t]       = vr;
            ws[256 + j * 16 + t] = vi;
        }
    }

    // WpT pack: ws[512 + f*4 + q] = Wp[q*64 + f], f = t
    for (int q = 0; q < 4; q++) ws[512 + t * 4 + q] = Wp[q * 64 + t];
    if (t < 4) ws[768 + t] = bp[t];

    // MLP pack, row j = t
    ws[772 + t * 6 + 0] = W1[t * 4 + 0];
    ws[772 + t * 6 + 1] = W1[t * 4 + 1];
    ws[772 + t * 6 + 2] = W1[t * 4 + 2];
    ws[772 + t * 6 + 3] = W1[t * 4 + 3];
    ws[772 + t * 6 + 4] = b1[t];
    ws[772 + t * 6 + 5] = W2[t];
    if (t == 0) ws[1156] = b2[0];
}

// ---------------- main kernel ----------------
// R3 structure (best so far): block = 256 threads = 256 rows, two 32-column
// stages through LDS, stride-33 rows (conflict-free scalar b32 writes/reads,
// every global dwordx4 covers 8 full 128-B lines).
// R6 change: ALL 16 global loads issued up front (stage-1 prefetched into
// registers), removing the inter-stage HBM-latency bubble.
// Do NOT use stride-36/b128 LDS (R4: 8-way conflicts, -12 us) or per-lane
// 64-B-stride loads (R5: 32 lines/instr, -7 us).

__global__ __launch_bounds__(256, 4) void qmain_kernel(const float* __restrict__ x,
                                                       const float* __restrict__ cb,
                                                       float* __restrict__ out,
                                                       int B) {
    __shared__ float tile[256 * 33];
    const int t = threadIdx.x;
    const long row0 = (long)blockIdx.x * 256;
    const float* xb = x + row0 * 64;

    // cooperative mapping: per r-iter, 256 threads cover 256x(32/8)... lane
    // t covers row = (r*1024 + t*4)>>5, col = (t*4)&31.
    const int lrow = t >> 3;        // row within 32-row slab
    const int lcol = (t & 7) * 4;   // 0,4,...,28

    // ---- issue ALL global loads up front (stage 0 + stage 1 prefetch) ----
    float4 v0[8], v1[8];
    #pragma unroll
    for (int r = 0; r < 8; r++) {
        int row = r * 32 + lrow;
        v0[r] = *reinterpret_cast<const float4*>(xb + row * 64 + lcol);
    }
    #pragma unroll
    for (int r = 0; r < 8; r++) {
        int row = r * 32 + lrow;
        v1[r] = *reinterpret_cast<const float4*>(xb + row * 64 + 32 + lcol);
    }

    float ang[4];
    #pragma unroll
    for (int q = 0; q < 4; q++) ang[q] = cb[768 + q];

    // ---- stage 0: scalar LDS writes (stride 33, conflict-free), consume ----
    #pragma unroll
    for (int r = 0; r < 8; r++) {
        int row = r * 32 + lrow;
        float* dst = &tile[row * 33 + lcol];
        dst[0] = v0[r].x; dst[1] = v0[r].y; dst[2] = v0[r].z; dst[3] = v0[r].w;
    }
    __syncthreads();
    {
        const float* myrow = &tile[t * 33];
        #pragma unroll
        for (int i = 0; i < 32; i++) {
            float xv = myrow[i];
            const float* w = &cb[512 + i * 4];
            #pragma unroll
            for (int q = 0; q < 4; q++) ang[q] = fmaf(xv, w[q], ang[q]);
        }
    }
    __syncthreads();

    // ---- stage 1: from prefetched registers ----
    #pragma unroll
    for (int r = 0; r < 8; r++) {
        int row = r * 32 + lrow;
        float* dst = &tile[row * 33 + lcol];
        dst[0] = v1[r].x; dst[1] = v1[r].y; dst[2] = v1[r].z; dst[3] = v1[r].w;
    }
    __syncthreads();
    {
        const float* myrow = &tile[t * 33];
        #pragma unroll
        for (int i = 0; i < 32; i++) {
            float xv = myrow[i];
            const float* w = &cb[512 + (32 + i) * 4];
            #pragma unroll
            for (int q = 0; q < 4; q++) ang[q] = fmaf(xv, w[q], ang[q]);
        }
    }

    // ---- RX product-state magnitudes m[16] ----
    float c[4], s4[4];
    #pragma unroll
    for (int q = 0; q < 4; q++) {
        __sincosf(0.5f * ang[q], &s4[q], &c[q]);
    }
    float pre[4]  = { c[0] * c[1], c[0] * s4[1], s4[0] * c[1], s4[0] * s4[1] };
    float post[4] = { c[2] * c[3], c[2] * s4[3], s4[2] * c[3], s4[2] * s4[3] };
    float m[16];
    #pragma unroll
    for (int k = 0; k < 16; k++) m[k] = pre[k >> 2] * post[k & 3];

    // ---- phi = V m ; p = |phi|^2 ; z = signed sums ----
    float z0 = 0.f, z1 = 0.f, z2 = 0.f, z3 = 0.f;
    #pragma unroll
    for (int j = 0; j < 16; j++) {
        const float* vr = &cb[j * 16];
        const float* vi = &cb[256 + j * 16];
        float re = 0.f, im = 0.f;
        #pragma unroll
        for (int k = 0; k < 16; k++) {
            re = fmaf(vr[k], m[k], re);
            im = fmaf(vi[k], m[k], im);
        }
        float p = re * re + im * im;
        z0 += (j & 8) ? -p : p;
        z1 += (j & 4) ? -p : p;
        z2 += (j & 2) ? -p : p;
        z3 += (j & 1) ? -p : p;
    }

    // ---- MLP: out = W2 @ relu(W1 @ z + b1) + b2 ----
    float acc = cb[1156];
    #pragma unroll
    for (int j = 0; j < 64; j++) {
        const float* mp = &cb[772 + j * 6];
        float h = mp[4];
        h = fmaf(mp[0], z0, h);
        h = fmaf(mp[1], z1, h);
        h = fmaf(mp[2], z2, h);
        h = fmaf(mp[3], z3, h);
        h = fmaxf(h, 0.f);
        acc = fmaf(mp[5], h, acc);
    }
    out[row0 + t] = acc;
}

// ---------------- launch ----------------

extern "C" void kernel_launch(void* const* d_in, const int* in_sizes, int n_in,
                              void* d_out, int out_size, void* d_ws, size_t ws_size,
                              hipStream_t stream) {
    const float* x  = (const float*)d_in[0];
    const float* Wp = (const float*)d_in[1];
    const float* bp = (const float*)d_in[2];
    const float* wq = (const float*)d_in[3];
    const float* W1 = (const float*)d_in[4];
    const float* b1 = (const float*)d_in[5];
    const float* W2 = (const float*)d_in[6];
    const float* b2 = (const float*)d_in[7];
    float* ws = (float*)d_ws;
    float* out = (float*)d_out;

    int B = in_sizes[0] / 64;   // 262144

    precompute_kernel<<<1, 64, 0, stream>>>(Wp, bp, wq, W1, b1, W2, b2, ws);

    int grid = B / 256;   // 1024 blocks, 256 rows each
    qmain_kernel<<<grid, 256, 0, stream>>>(x, ws, out, B);
}